// Round 1
// baseline (1237.296 us; speedup 1.0000x reference)
//
#include <hip/hip_runtime.h>
#include <cstdint>

#define W 2048
#define H 512
#define ROWD 8                       // dwords per position (32B stride, b128-aligned)
#define BUFSZ (2050*ROWD + 8)        // per-buffer dwords (ghost pos each side + pad)

// LDS per-position channel layout (halves):
//   dw0=(c0,c1) dw1=(c2,c3) dw2=(c8,c9) dw3=(x1,x2) | dw4=(c4,c5) dw5=(c6,c7) dw6=dw7=0
// B-fragment k-order: hh=0 -> k0..7 = c0,c1,c2,c3,c8,c9,x1,x2  (one b128 at +0)
//                     hh=1 -> k8..11 = c4,c5,c6,c7; k12..15 dead (one b128 at +16, pads=0)

typedef __fp16 h2    __attribute__((ext_vector_type(2)));
typedef __fp16 f16x8 __attribute__((ext_vector_type(8)));
typedef float  f32x16 __attribute__((ext_vector_type(16)));

static __device__ __forceinline__ h2 as_h2(uint32_t u){ union{uint32_t u; h2 h;} x; x.u=u; return x.h; }
static __device__ __forceinline__ uint32_t as_u32(h2 h){ union{uint32_t u; h2 h;} x; x.h=h; return x.u; }

__global__ __launch_bounds__(1024, 1) void recurrent_kernel(
    const float* __restrict__ x,
    const float* __restrict__ w1, const float* __restrict__ b1,
    const float* __restrict__ w2, const float* __restrict__ b2,
    const float* __restrict__ wl, const float* __restrict__ bl,
    const float* __restrict__ wo, const float* __restrict__ bo,
    float* __restrict__ out)
{
    extern __shared__ uint32_t lds[];   // 2 x BUFSZ dwords, double-buffered rows
    const int tid  = threadIdx.x;
    const int b    = blockIdx.x;
    const int lane = tid & 63;
    const int wv   = tid >> 6;       // wave 0..15
    const int m    = lane & 31;      // MFMA: out-channel row / position col
    const int hh   = lane >> 5;      // k-group select

    for (int i = tid; i < 2*BUFSZ; i += 1024) lds[i] = 0;

    // ---- A fragments: weights resident in VGPRs for all 512 steps ----
    // k-channel permutation matches the LDS layout above.
    f16x8 afrag[3];
    #pragma unroll
    for (int tap = 0; tap < 3; ++tap)
        #pragma unroll
        for (int j = 0; j < 8; ++j) {
            int k = (hh == 0) ? (j < 4 ? j : j + 4)      // 0,1,2,3,8,9,10,11
                              : (j < 4 ? j + 4 : 12);    // 4,5,6,7, dead
            float v = (m < 10 && k < 12) ? wl[(m*12 + k)*3 + tap] : 0.f;
            afrag[tap][j] = (__fp16)v;
        }
    // 1x1-conv weight pairs matching this half-wave's D channels (D mapping unchanged)
    h2 wop0, wop1, wop2;
    if (hh == 0) {
        wop0 = __builtin_amdgcn_cvt_pkrtz(wo[0], wo[1]);
        wop1 = __builtin_amdgcn_cvt_pkrtz(wo[2], wo[3]);
        wop2 = __builtin_amdgcn_cvt_pkrtz(wo[8], wo[9]);
    } else {
        wop0 = __builtin_amdgcn_cvt_pkrtz(wo[4], wo[5]);
        wop1 = __builtin_amdgcn_cvt_pkrtz(wo[6], wo[7]);
        wop2 = __builtin_amdgcn_cvt_pkrtz(0.f, 0.f);
    }
    // bias preloaded into the accumulator (D rows 0..7 are the valid channels)
    f32x16 bias16;
    #pragma unroll
    for (int r = 0; r < 16; ++r) {
        int ch = (r & 3) + 8*(r >> 2) + 4*hh;
        bias16[r] = (r < 8 && ch < 10) ? bl[ch] : 0.f;
    }
    const float bov = bo[0];
    const int bpaddr = (lane ^ 32) << 2;

    const float* x1b = x + (((size_t)b*3 + 1)*H)*W;
    const float* x2b = x + (((size_t)b*3 + 2)*H)*W;
    float* outb = out + (size_t)b*H*W;

    __syncthreads();   // LDS zeros visible before init writes

    // ---- init: row0 = relu(conv2('same', relu(conv1('valid', first_in)))) -> buf0 ----
    {
        const float* f0p = x + (((size_t)b*3 + 0)*H + (H-1))*W;  // x[b,0,-1,:]
        const float* f1p = x1b;                                   // x[b,1,0,:]
        const float* f2p = x2b;                                   // x[b,2,0,:]
        float fi[3][6];
        const int v0 = 2*tid - 1;      // first_in base position (w-2 of first output)
        #pragma unroll
        for (int l = 0; l < 6; ++l) {
            int v = v0 + l;
            bool ok = (v >= 0) && (v < W);
            fi[0][l] = ok ? f0p[v] : 0.f;
            fi[1][l] = ok ? f1p[v] : 0.f;
            fi[2][l] = ok ? f2p[v] : 0.f;
        }
        float h1v[5][4];
        #pragma unroll
        for (int c = 0; c < 5; ++c)
            #pragma unroll
            for (int i6 = 0; i6 < 4; ++i6) {
                int u = v0 + i6;               // h1 position, valid 0..2045 else 'same' pad 0
                float a = b1[c];
                #pragma unroll
                for (int j = 0; j < 3; ++j)
                    #pragma unroll
                    for (int k = 0; k < 3; ++k)
                        a += w1[(c*3 + j)*3 + k] * fi[j][i6 + k];
                h1v[c][i6] = (u >= 0 && u <= W-3) ? fmaxf(a, 0.f) : 0.f;
            }
        #pragma unroll
        for (int mm = 0; mm < 2; ++mm) {
            int w = 2*tid + 1 + mm;            // interior positions 1..2046
            if (w <= W - 2) {
                float h2c[10];
                #pragma unroll
                for (int c2 = 0; c2 < 10; ++c2) {
                    float a = b2[c2];
                    #pragma unroll
                    for (int c = 0; c < 5; ++c)
                        #pragma unroll
                        for (int k = 0; k < 3; ++k)
                            a += w2[(c2*5 + c)*3 + k] * h1v[c][mm + k];   // h1[w-2..w]
                    h2c[c2] = fmaxf(a, 0.f);
                }
                uint32_t* rp = lds + (w + 1)*ROWD;
                rp[0] = as_u32(__builtin_amdgcn_cvt_pkrtz(h2c[0], h2c[1]));
                rp[1] = as_u32(__builtin_amdgcn_cvt_pkrtz(h2c[2], h2c[3]));
                rp[2] = as_u32(__builtin_amdgcn_cvt_pkrtz(h2c[8], h2c[9]));
                rp[4] = as_u32(__builtin_amdgcn_cvt_pkrtz(h2c[4], h2c[5]));
                rp[5] = as_u32(__builtin_amdgcn_cvt_pkrtz(h2c[6], h2c[7]));
            }
        }
        // x channels for step 1 -> buf0 (dw3)
        #pragma unroll
        for (int i = 0; i < 2; ++i) {
            int p = tid + 1024*i;
            lds[(p + 1)*ROWD + 3] = as_u32(__builtin_amdgcn_cvt_pkrtz(x1b[W + p], x2b[W + p]));
        }
    }
    __syncthreads();

    // ---- out[0] from row0 ----
    {
        h2 wo01 = __builtin_amdgcn_cvt_pkrtz(wo[0], wo[1]);
        h2 wo23 = __builtin_amdgcn_cvt_pkrtz(wo[2], wo[3]);
        h2 wo45 = __builtin_amdgcn_cvt_pkrtz(wo[4], wo[5]);
        h2 wo67 = __builtin_amdgcn_cvt_pkrtz(wo[6], wo[7]);
        h2 wo89 = __builtin_amdgcn_cvt_pkrtz(wo[8], wo[9]);
        #pragma unroll
        for (int i = 0; i < 2; ++i) {
            int p = 2*tid + i;
            const uint32_t* rp = lds + (p + 1)*ROWD;
            uint4 a = *(const uint4*)rp;        // c01, c23, c89, x-pair
            uint2 c = *(const uint2*)(rp + 4);  // c45, c67
            float s = __builtin_amdgcn_fdot2(wo01, as_h2(a.x), bov, false);
            s = __builtin_amdgcn_fdot2(wo23, as_h2(a.y), s, false);
            s = __builtin_amdgcn_fdot2(wo89, as_h2(a.z), s, false);
            s = __builtin_amdgcn_fdot2(wo45, as_h2(c.x), s, false);
            s = __builtin_amdgcn_fdot2(wo67, as_h2(c.y), s, false);
            outb[p] = s;
        }
    }

    // ---- recurrence: single barrier per step (double-buffered rows) ----
    #pragma unroll 1
    for (int t = 1; t < H; ++t) {
        const uint32_t* rb = lds + ((t - 1) & 1)*BUFSZ;   // row t-1 + x[t]
        uint32_t*       wb = lds + (t & 1)*BUFSZ;         // row t   + x[t+1]

        // prefetch x[t+1] (raw floats; converted in phase B so loads get cover)
        float xf1[2], xf2[2];
        const bool pf = (t + 1 < H);
        if (pf) {
            const float* r1 = x1b + (size_t)(t + 1)*W;
            const float* r2 = x2b + (size_t)(t + 1)*W;
            #pragma unroll
            for (int i = 0; i < 2; ++i) {
                int p = tid + 1024*i;
                xf1[i] = r1[p];
                xf2[i] = r2[p];
            }
        }

        // phase A: issue all B-fragment loads (one b128 per tile-tap), then MFMA chains
        uint4 bu[4][3];
        #pragma unroll
        for (int ti = 0; ti < 4; ++ti) {
            const int n = (wv*4 + ti)*32 + m;
            const uint32_t* pb = rb + n*ROWD + 4*hh;
            #pragma unroll
            for (int tap = 0; tap < 3; ++tap)
                bu[ti][tap] = *(const uint4*)(pb + tap*ROWD);
        }
        uint32_t stash[4][3];
        float pv[4];
        #pragma unroll
        for (int ti = 0; ti < 4; ++ti) {
            f32x16 acc = bias16;
            #pragma unroll
            for (int tap = 0; tap < 3; ++tap) {
                union { uint4 u; f16x8 v; } c;
                c.u = bu[ti][tap];
                acc = __builtin_amdgcn_mfma_f32_32x32x16_f16(afrag[tap], c.v, acc, 0, 0, 0);
            }
            float f0 = fmaxf(acc[0], 0.f), f1 = fmaxf(acc[1], 0.f);
            float f2 = fmaxf(acc[2], 0.f), f3 = fmaxf(acc[3], 0.f);
            float f4 = fmaxf(acc[4], 0.f), f5 = fmaxf(acc[5], 0.f);
            uint32_t s0 = as_u32(__builtin_amdgcn_cvt_pkrtz(f0, f1));
            uint32_t s1 = as_u32(__builtin_amdgcn_cvt_pkrtz(f2, f3));
            uint32_t s2 = as_u32(__builtin_amdgcn_cvt_pkrtz(f4, f5));
            stash[ti][0] = s0; stash[ti][1] = s1; stash[ti][2] = s2;
            // fused 1x1 conv: this half's channels + other half via bpermute
            float pc = __builtin_amdgcn_fdot2(wop2, as_h2(s2),
                       __builtin_amdgcn_fdot2(wop1, as_h2(s1),
                       __builtin_amdgcn_fdot2(wop0, as_h2(s0), 0.f, false), false), false);
            int pi = __builtin_amdgcn_ds_bpermute(bpaddr, __builtin_bit_cast(int, pc));
            pv[ti] = pc + __builtin_bit_cast(float, pi);
        }

        // phase B: write row t into wb (no conflict with rb)
        // hh=0 lanes produce c0..3 (dw0,1) + c8,9 (dw2); hh=1 lanes produce c4..7 (dw4,5)
        #pragma unroll
        for (int ti = 0; ti < 4; ++ti) {
            const int n = (wv*4 + ti)*32 + m;
            if (n != 0 && n != W-1) {
                uint32_t* rp = wb + (n + 1)*ROWD + 4*hh;
                uint2 wr; wr.x = stash[ti][0]; wr.y = stash[ti][1];
                *(uint2*)rp = wr;
                if (hh == 0) rp[2] = stash[ti][2];
            }
        }
        if (pf) {
            #pragma unroll
            for (int i = 0; i < 2; ++i) {
                int p = tid + 1024*i;
                wb[(p + 1)*ROWD + 3] = as_u32(__builtin_amdgcn_cvt_pkrtz(xf1[i], xf2[i]));
            }
        }

        __syncthreads();   // row t visible; only barrier in the step

        // deferred out-store: drains at the NEXT step's barrier (a full phase A away)
        // pv is identical in both half-waves -> split the 4 tiles across hh (2 stores/lane)
        #pragma unroll
        for (int i = 0; i < 2; ++i) {
            const int ti = 2*hh + i;
            const int n = (wv*4 + ti)*32 + m;
            float val = (n == 0 || n == W-1) ? bov : pv[ti] + bov;
            outb[(size_t)t*W + n] = val;
        }
    }
}

extern "C" void kernel_launch(void* const* d_in, const int* in_sizes, int n_in,
                              void* d_out, int out_size, void* d_ws, size_t ws_size,
                              hipStream_t stream)
{
    const float* x  = (const float*)d_in[0];
    const float* w1 = (const float*)d_in[1];
    const float* b1 = (const float*)d_in[2];
    const float* w2 = (const float*)d_in[3];
    const float* b2 = (const float*)d_in[4];
    const float* wl = (const float*)d_in[5];
    const float* bl = (const float*)d_in[6];
    const float* wo = (const float*)d_in[7];
    const float* bo = (const float*)d_in[8];
    float* out = (float*)d_out;

    const int shbytes = 2 * BUFSZ * sizeof(uint32_t);   // ~128.2 KB
    hipFuncSetAttribute((const void*)recurrent_kernel,
                        hipFuncAttributeMaxDynamicSharedMemorySize, shbytes);
    recurrent_kernel<<<8, 1024, shbytes, stream>>>(x, w1, b1, w2, b2, wl, bl, wo, bo, out);
}

// Round 2
// 1090.847 us; speedup vs baseline: 1.1343x; 1.1343x over previous
//
#include <hip/hip_runtime.h>
#include <cstdint>

#define W 2048
#define H 512
// Split-array LDS layout, per buffer:
//   arrA: 2050 slots x 4 dwords (16B): {c01, c23, c45, c67}   -> hh0 b128 reads
//   arrB: 2050 slots x 2 dwords (8B):  {c89, x-pair}          -> hh1 b64 reads
// slot q holds position p = q-1 (ghost zero slots at q=0 and q=2049)
#define ABASE 0
#define BBASE (2050*4)
#define BUFD  (2050*4 + 2050*2)   // 12300 dwords per buffer

typedef __fp16 h2    __attribute__((ext_vector_type(2)));
typedef __fp16 f16x8 __attribute__((ext_vector_type(8)));
typedef float  f32x16 __attribute__((ext_vector_type(16)));

static __device__ __forceinline__ h2 as_h2(uint32_t u){ union{uint32_t u; h2 h;} x; x.u=u; return x.h; }
static __device__ __forceinline__ uint32_t as_u32(h2 h){ union{uint32_t u; h2 h;} x; x.h=h; return x.u; }

__global__ __launch_bounds__(1024, 1) void recurrent_kernel(
    const float* __restrict__ x,
    const float* __restrict__ w1, const float* __restrict__ b1,
    const float* __restrict__ w2, const float* __restrict__ b2,
    const float* __restrict__ wl, const float* __restrict__ bl,
    const float* __restrict__ wo, const float* __restrict__ bo,
    float* __restrict__ out)
{
    extern __shared__ uint32_t lds[];   // 2 x BUFD dwords, double-buffered rows
    const int tid  = threadIdx.x;
    const int b    = blockIdx.x;
    const int lane = tid & 63;
    const int wv   = tid >> 6;       // wave 0..15
    const int m    = lane & 31;      // MFMA: out-channel row / position col
    const int hh   = lane >> 5;      // k-group select

    for (int i = tid; i < 2*BUFD; i += 1024) lds[i] = 0;

    // ---- A fragments: weights resident in VGPRs for all 512 steps ----
    // k = 8*hh + j ; channels 0-9 = prev row, 10-11 = x1,x2 (identical to baseline)
    f16x8 afrag[3];
    #pragma unroll
    for (int tap = 0; tap < 3; ++tap)
        #pragma unroll
        for (int j = 0; j < 8; ++j) {
            int k = 8*hh + j;
            float v = (m < 10 && k < 12) ? wl[(m*12 + k)*3 + tap] : 0.f;
            afrag[tap][j] = (__fp16)v;
        }
    // 1x1-conv weight pairs matching this half-wave's D channels
    h2 wop0, wop1, wop2;
    if (hh == 0) {
        wop0 = __builtin_amdgcn_cvt_pkrtz(wo[0], wo[1]);
        wop1 = __builtin_amdgcn_cvt_pkrtz(wo[2], wo[3]);
        wop2 = __builtin_amdgcn_cvt_pkrtz(wo[8], wo[9]);
    } else {
        wop0 = __builtin_amdgcn_cvt_pkrtz(wo[4], wo[5]);
        wop1 = __builtin_amdgcn_cvt_pkrtz(wo[6], wo[7]);
        wop2 = __builtin_amdgcn_cvt_pkrtz(0.f, 0.f);
    }
    // bias preloaded into the accumulator (D rows 0..7 are the valid channels)
    f32x16 bias16;
    #pragma unroll
    for (int r = 0; r < 16; ++r) {
        int ch = (r & 3) + 8*(r >> 2) + 4*hh;
        bias16[r] = (r < 8 && ch < 10) ? bl[ch] : 0.f;
    }
    const float bov = bo[0];
    const int bpaddr = (lane ^ 32) << 2;

    const float* x1b = x + (((size_t)b*3 + 1)*H)*W;
    const float* x2b = x + (((size_t)b*3 + 2)*H)*W;
    float* outb = out + (size_t)b*H*W;

    __syncthreads();   // LDS zeros visible before init writes

    // ---- init: row0 = relu(conv2('same', relu(conv1('valid', first_in)))) -> buf0 ----
    {
        const float* f0p = x + (((size_t)b*3 + 0)*H + (H-1))*W;  // x[b,0,-1,:]
        const float* f1p = x1b;                                   // x[b,1,0,:]
        const float* f2p = x2b;                                   // x[b,2,0,:]
        float fi[3][6];
        const int v0 = 2*tid - 1;      // first_in base position (w-2 of first output)
        #pragma unroll
        for (int l = 0; l < 6; ++l) {
            int v = v0 + l;
            bool ok = (v >= 0) && (v < W);
            fi[0][l] = ok ? f0p[v] : 0.f;
            fi[1][l] = ok ? f1p[v] : 0.f;
            fi[2][l] = ok ? f2p[v] : 0.f;
        }
        float h1v[5][4];
        #pragma unroll
        for (int c = 0; c < 5; ++c)
            #pragma unroll
            for (int i6 = 0; i6 < 4; ++i6) {
                int u = v0 + i6;               // h1 position, valid 0..2045 else 'same' pad 0
                float a = b1[c];
                #pragma unroll
                for (int j = 0; j < 3; ++j)
                    #pragma unroll
                    for (int k = 0; k < 3; ++k)
                        a += w1[(c*3 + j)*3 + k] * fi[j][i6 + k];
                h1v[c][i6] = (u >= 0 && u <= W-3) ? fmaxf(a, 0.f) : 0.f;
            }
        #pragma unroll
        for (int mm = 0; mm < 2; ++mm) {
            int w = 2*tid + 1 + mm;            // interior positions 1..2046
            if (w <= W - 2) {
                float h2c[10];
                #pragma unroll
                for (int c2 = 0; c2 < 10; ++c2) {
                    float a = b2[c2];
                    #pragma unroll
                    for (int c = 0; c < 5; ++c)
                        #pragma unroll
                        for (int k = 0; k < 3; ++k)
                            a += w2[(c2*5 + c)*3 + k] * h1v[c][mm + k];   // h1[w-2..w]
                    h2c[c2] = fmaxf(a, 0.f);
                }
                uint32_t* ra = lds + ABASE + 4*(w + 1);
                uint4 wr;
                wr.x = as_u32(__builtin_amdgcn_cvt_pkrtz(h2c[0], h2c[1]));
                wr.y = as_u32(__builtin_amdgcn_cvt_pkrtz(h2c[2], h2c[3]));
                wr.z = as_u32(__builtin_amdgcn_cvt_pkrtz(h2c[4], h2c[5]));
                wr.w = as_u32(__builtin_amdgcn_cvt_pkrtz(h2c[6], h2c[7]));
                *(uint4*)ra = wr;
                lds[BBASE + 2*(w + 1)] = as_u32(__builtin_amdgcn_cvt_pkrtz(h2c[8], h2c[9]));
            }
        }
        // x channels for step 1 -> buf0 (arrB dw1)
        #pragma unroll
        for (int i = 0; i < 2; ++i) {
            int p = tid + 1024*i;
            lds[BBASE + 2*(p + 1) + 1] = as_u32(__builtin_amdgcn_cvt_pkrtz(x1b[W + p], x2b[W + p]));
        }
    }
    __syncthreads();

    // ---- out[0] from row0 ----
    {
        h2 wo01 = __builtin_amdgcn_cvt_pkrtz(wo[0], wo[1]);
        h2 wo23 = __builtin_amdgcn_cvt_pkrtz(wo[2], wo[3]);
        h2 wo45 = __builtin_amdgcn_cvt_pkrtz(wo[4], wo[5]);
        h2 wo67 = __builtin_amdgcn_cvt_pkrtz(wo[6], wo[7]);
        h2 wo89 = __builtin_amdgcn_cvt_pkrtz(wo[8], wo[9]);
        #pragma unroll
        for (int i = 0; i < 2; ++i) {
            int p = 2*tid + i;
            const uint32_t* ra = lds + ABASE + 4*(p + 1);
            uint4 a = *(const uint4*)ra;               // c01,c23,c45,c67
            uint32_t e = lds[BBASE + 2*(p + 1)];       // c89
            float s = __builtin_amdgcn_fdot2(wo01, as_h2(a.x), bov, false);
            s = __builtin_amdgcn_fdot2(wo23, as_h2(a.y), s, false);
            s = __builtin_amdgcn_fdot2(wo45, as_h2(a.z), s, false);
            s = __builtin_amdgcn_fdot2(wo67, as_h2(a.w), s, false);
            s = __builtin_amdgcn_fdot2(wo89, as_h2(e),   s, false);
            outb[p] = s;
        }
    }

    // ---- recurrence: single barrier per step (double-buffered rows) ----
    #pragma unroll 1
    for (int t = 1; t < H; ++t) {
        const uint32_t* rb = lds + ((t - 1) & 1)*BUFD;   // row t-1 + x[t]
        uint32_t*       wb = lds + (t & 1)*BUFD;         // row t   + x[t+1]

        // prefetch x[t+1] (raw floats; converted in phase B so loads get cover)
        float xf1[2], xf2[2];
        const bool pf = (t + 1 < H);
        if (pf) {
            const float* r1 = x1b + (size_t)(t + 1)*W;
            const float* r2 = x2b + (size_t)(t + 1)*W;
            #pragma unroll
            for (int i = 0; i < 2; ++i) {
                int p = tid + 1024*i;
                xf1[i] = r1[p];
                xf2[i] = r2[p];
            }
        }

        // phase A: issue all B-fragment loads, then MFMA chains.
        // hh0: one aligned b128 per tap from arrA (stride 16B -> conflict-free)
        // hh1: three b64 from arrB (stride 8B -> conflict-free); taps share regs,
        //      k12-15 junk multiplies zero A-weights.
        uint4 bu[4][3];
        if (hh == 0) {
            #pragma unroll
            for (int ti = 0; ti < 4; ++ti) {
                const int n = (wv*4 + ti)*32 + m;
                const uint32_t* pa = rb + ABASE + 4*n;
                #pragma unroll
                for (int tap = 0; tap < 3; ++tap)
                    bu[ti][tap] = *(const uint4*)(pa + 4*tap);
            }
        } else {
            #pragma unroll
            for (int ti = 0; ti < 4; ++ti) {
                const int n = (wv*4 + ti)*32 + m;
                const uint32_t* pb = rb + BBASE + 2*n;
                uint2 v0 = *(const uint2*)pb;         // slot n   : c89,x
                uint2 v1 = *(const uint2*)(pb + 2);   // slot n+1
                uint2 v2 = *(const uint2*)(pb + 4);   // slot n+2
                bu[ti][0].x = v0.x; bu[ti][0].y = v0.y; bu[ti][0].z = v1.x; bu[ti][0].w = v1.y;
                bu[ti][1].x = v1.x; bu[ti][1].y = v1.y; bu[ti][1].z = v2.x; bu[ti][1].w = v2.y;
                bu[ti][2].x = v2.x; bu[ti][2].y = v2.y; bu[ti][2].z = v0.x; bu[ti][2].w = v0.y;
            }
        }
        uint32_t stash[4][3];
        float pv[4];
        #pragma unroll
        for (int ti = 0; ti < 4; ++ti) {
            f32x16 acc = bias16;
            #pragma unroll
            for (int tap = 0; tap < 3; ++tap) {
                union { uint4 u; f16x8 v; } c;
                c.u = bu[ti][tap];
                acc = __builtin_amdgcn_mfma_f32_32x32x16_f16(afrag[tap], c.v, acc, 0, 0, 0);
            }
            float f0 = fmaxf(acc[0], 0.f), f1 = fmaxf(acc[1], 0.f);
            float f2 = fmaxf(acc[2], 0.f), f3 = fmaxf(acc[3], 0.f);
            float f4 = fmaxf(acc[4], 0.f), f5 = fmaxf(acc[5], 0.f);
            uint32_t s0 = as_u32(__builtin_amdgcn_cvt_pkrtz(f0, f1));
            uint32_t s1 = as_u32(__builtin_amdgcn_cvt_pkrtz(f2, f3));
            uint32_t s2 = as_u32(__builtin_amdgcn_cvt_pkrtz(f4, f5));
            stash[ti][0] = s0; stash[ti][1] = s1; stash[ti][2] = s2;
            // fused 1x1 conv: this half's channels + other half via bpermute
            float pc = __builtin_amdgcn_fdot2(wop2, as_h2(s2),
                       __builtin_amdgcn_fdot2(wop1, as_h2(s1),
                       __builtin_amdgcn_fdot2(wop0, as_h2(s0), 0.f, false), false), false);
            int pi = __builtin_amdgcn_ds_bpermute(bpaddr, __builtin_bit_cast(int, pc));
            pv[ti] = pc + __builtin_bit_cast(float, pi);
        }

        // phase B: write row t into wb (no conflict with rb)
        // hh0 produced c0-3 (arrA dw0,1) + c8,9 (arrB dw0); hh1 produced c4-7 (arrA dw2,3)
        #pragma unroll
        for (int ti = 0; ti < 4; ++ti) {
            const int n = (wv*4 + ti)*32 + m;
            if (n != 0 && n != W-1) {
                uint32_t* ra = wb + ABASE + 4*(n + 1) + 2*hh;
                uint2 wr; wr.x = stash[ti][0]; wr.y = stash[ti][1];
                *(uint2*)ra = wr;
                if (hh == 0) wb[BBASE + 2*(n + 1)] = stash[ti][2];
            }
        }
        if (pf) {
            #pragma unroll
            for (int i = 0; i < 2; ++i) {
                int p = tid + 1024*i;
                wb[BBASE + 2*(p + 1) + 1] = as_u32(__builtin_amdgcn_cvt_pkrtz(xf1[i], xf2[i]));
            }
        }

        __syncthreads();   // row t visible; only barrier in the step

        // deferred out-store: drains at the NEXT step's barrier (a full phase A away)
        // pv is identical in both half-waves -> split the 4 tiles across hh
        #pragma unroll
        for (int i = 0; i < 2; ++i) {
            const int ti = 2*hh + i;
            const int n = (wv*4 + ti)*32 + m;
            float val = (n == 0 || n == W-1) ? bov : pv[ti] + bov;
            outb[(size_t)t*W + n] = val;
        }
    }
}

extern "C" void kernel_launch(void* const* d_in, const int* in_sizes, int n_in,
                              void* d_out, int out_size, void* d_ws, size_t ws_size,
                              hipStream_t stream)
{
    const float* x  = (const float*)d_in[0];
    const float* w1 = (const float*)d_in[1];
    const float* b1 = (const float*)d_in[2];
    const float* w2 = (const float*)d_in[3];
    const float* b2 = (const float*)d_in[4];
    const float* wl = (const float*)d_in[5];
    const float* bl = (const float*)d_in[6];
    const float* wo = (const float*)d_in[7];
    const float* bo = (const float*)d_in[8];
    float* out = (float*)d_out;

    const int shbytes = 2 * BUFD * sizeof(uint32_t);   // 98.4 KB
    hipFuncSetAttribute((const void*)recurrent_kernel,
                        hipFuncAttributeMaxDynamicSharedMemorySize, shbytes);
    recurrent_kernel<<<8, 1024, shbytes, stream>>>(x, w1, b1, w2, b2, wl, bl, wo, bo, out);
}